// Round 7
// baseline (42.598 us; speedup 1.0000x reference)
//
#include <hip/hip_runtime.h>
#include <math.h>

typedef float float4v __attribute__((ext_vector_type(4)));
typedef float float2v __attribute__((ext_vector_type(2)));

__device__ __forceinline__ unsigned rotl32(unsigned v, int n) {
  return (v << n) | (v >> (32 - n));
}

__device__ __forceinline__ float frcp(float x) { return __builtin_amdgcn_rcpf(x); }

__device__ __forceinline__ float ftanh(float x) {
  float t = __expf(2.0f * x);
  return 1.0f - 2.0f * frcp(t + 1.0f);
}

__device__ __forceinline__ float fsigmoid(float x) {
  return frcp(1.0f + __expf(-x));
}

// jax.random.normal(key(42), (n,), f32)[idx], partitionable threefry scheme.
__device__ __forceinline__ float jax_threefry_normal42_part(unsigned idx) {
  const unsigned ks0 = 0u;
  const unsigned ks1 = 42u;
  const unsigned ks2 = 0x1BD11BDAu ^ 42u;
  unsigned x0 = 0u + ks0;
  unsigned x1 = idx + ks1;
  const unsigned ks[3] = {ks0, ks1, ks2};
  const int rA[4] = {13, 15, 26, 6};
  const int rB[4] = {17, 29, 16, 24};
#pragma unroll
  for (int i = 0; i < 5; ++i) {
    const int* r = (i & 1) ? rB : rA;
#pragma unroll
    for (int k = 0; k < 4; ++k) {
      x0 += x1;
      x1 = rotl32(x1, r[k]);
      x1 ^= x0;
    }
    x0 += ks[(i + 1) % 3];
    x1 += ks[(i + 2) % 3] + (unsigned)(i + 1);
  }
  unsigned bits = x0 ^ x1;
  float u01 = __uint_as_float((bits >> 9) | 0x3f800000u) - 1.0f;
  const float lo = -0.99999994f;
  float u = fmaxf(lo, fmaf(u01, 2.0f, lo));
  float w = -__logf(1.0f - u * u);
  float p;
  if (w < 5.0f) {
    w = w - 2.5f;
    p = 2.81022636e-08f;
    p = fmaf(p, w, 3.43273939e-07f);
    p = fmaf(p, w, -3.5233877e-06f);
    p = fmaf(p, w, -4.39150654e-06f);
    p = fmaf(p, w, 0.00021858087f);
    p = fmaf(p, w, -0.00125372503f);
    p = fmaf(p, w, -0.00417768164f);
    p = fmaf(p, w, 0.246640727f);
    p = fmaf(p, w, 1.50140941f);
  } else {
    w = sqrtf(w) - 3.0f;
    p = -0.000200214257f;
    p = fmaf(p, w, 0.000100950558f);
    p = fmaf(p, w, 0.00134934322f);
    p = fmaf(p, w, -0.00367342844f);
    p = fmaf(p, w, 0.00573950773f);
    p = fmaf(p, w, -0.0076224613f);
    p = fmaf(p, w, 0.00943887047f);
    p = fmaf(p, w, 1.00167406f);
    p = fmaf(p, w, 2.83297682f);
  }
  return 1.41421354f * (p * u);
}

// Per-token computation: pred, pb[6], assignment
__device__ __forceinline__ void compute_token(
    const float* __restrict__ x, unsigned t,
    const float* __restrict__ rw, const float* __restrict__ rb,
    float& pred, float* pb, float& asn) {
  // router logits (f32)
  float lg[6];
#pragma unroll
  for (int d = 0; d < 6; ++d) {
    float acc = 0.0f;
#pragma unroll
    for (int h = 0; h < 16; ++h) acc = fmaf(x[h], rw[d * 16 + h], acc);
    lg[d] = acc + rb[d];
  }

  // argmax with f64 fallback for near-ties (match f64 np reference)
  int a1 = 0, a2 = 0;
  float b1 = lg[0], b2 = -1e30f;
#pragma unroll
  for (int d = 1; d < 6; ++d) {
    if (lg[d] > b1) { b2 = b1; a2 = a1; b1 = lg[d]; a1 = d; }
    else if (lg[d] > b2) { b2 = lg[d]; a2 = d; }
  }
  int amax = a1;
  if (b1 - b2 < 2e-5f) {
    double A = 0.0, B = 0.0;
#pragma unroll
    for (int h = 0; h < 16; ++h) {
      A = fma((double)x[h], (double)rw[a1 * 16 + h], A);
      B = fma((double)x[h], (double)rw[a2 * 16 + h], B);
    }
    A += (double)rb[a1];
    B += (double)rb[a2];
    amax = (B > A || (B == A && a2 < a1)) ? a2 : a1;
  }

  // softmax (routing_probs forward == probs_base)
  float m = lg[0];
#pragma unroll
  for (int d = 1; d < 6; ++d) m = fmaxf(m, lg[d]);
  float se = 0.0f;
  float eb[6];
#pragma unroll
  for (int d = 0; d < 6; ++d) { eb[d] = __expf(lg[d] - m); se += eb[d]; }
  float inv_se = frcp(se);
#pragma unroll
  for (int d = 0; d < 6; ++d) pb[d] = eb[d] * inv_se;

  // expert predictions
  float sum = 0.0f;
#pragma unroll
  for (int h = 0; h < 16; ++h) sum += x[h];
  float mean = sum * (1.0f / 16.0f);
  float ss = 0.0f;
#pragma unroll
  for (int h = 0; h < 16; ++h) {
    float dv = x[h] - mean;
    ss += dv * dv;
  }
  float stdv = sqrtf(ss * (1.0f / 15.0f));  // ddof=1

  float s4 = ((x[0] + x[1]) + x[2]) + x[3];
  float s6 = ((((x[0] + x[1]) + x[2]) + x[3]) + x[4]) + x[5];
  float s610 = ((x[6] + x[7]) + x[8]) + x[9];
  float s8 = s6 + x[6] + x[7];

  float sig = fsigmoid(mean);
  float p0 = ftanh(s4 * 0.25f) * (1.0f + stdv);
  float p1 = sig * 0.3f - 0.15f;
  float p2 = (s6 * (1.0f / 6.0f)) * 0.8f + __sinf((s610 * 0.25f) * 3.14159f) * 0.4f;
  float noise = jax_threefry_normal42_part(t) * 0.05f;
  float p3 = ftanh(s8 * 0.125f) * 0.9f + noise;
  float r4 = fmaxf(mean, 0.0f);
  float p4 = __expf(1.2f * __logf(r4)) + stdv * 2.5f - 0.5f;
  float p5 = sig * 0.4f + ftanh(stdv) * 0.2f;

  pred = (amax == 0) ? p0
       : (amax == 1) ? p1
       : (amax == 2) ? p2
       : (amax == 3) ? p3
       : (amax == 4) ? p4
                     : p5;
  asn = (float)amax;
}

__global__ __launch_bounds__(256) void finance_moe_kernel(
    const float* __restrict__ emb,  // (ntok, 16)
    const float* __restrict__ rw,   // (6, 16)
    const float* __restrict__ rb,   // (6,)
    float* __restrict__ out,        // [ntok pred][ntok*6 probs][ntok assign]
    int ntok) {
  int tid = blockIdx.x * blockDim.x + threadIdx.x;
  int t0 = tid * 2;
  if (t0 + 1 >= ntok) {
    if (t0 < ntok) {
      // odd tail (not hit for ntok = 2^20, kept for safety)
      float x[16];
      const float4v* e4 = reinterpret_cast<const float4v*>(emb) + (size_t)t0 * 4;
#pragma unroll
      for (int q = 0; q < 4; ++q) {
        float4v a = e4[q];
        x[q * 4 + 0] = a.x; x[q * 4 + 1] = a.y; x[q * 4 + 2] = a.z; x[q * 4 + 3] = a.w;
      }
      float pred, asn, pb[6];
      compute_token(x, (unsigned)t0, rw, rb, pred, pb, asn);
      out[t0] = pred;
      for (int d = 0; d < 6; ++d) out[ntok + t0 * 6 + d] = pb[d];
      out[(size_t)ntok * 7 + t0] = asn;
    }
    return;
  }

  // ---- load two tokens' embeddings (128B contiguous per thread) ----
  float xa[16], xb[16];
  {
    const float4v* e4 = reinterpret_cast<const float4v*>(emb) + (size_t)t0 * 4;
#pragma unroll
    for (int q = 0; q < 4; ++q) {
      float4v a = __builtin_nontemporal_load(e4 + q);
      xa[q * 4 + 0] = a.x; xa[q * 4 + 1] = a.y; xa[q * 4 + 2] = a.z; xa[q * 4 + 3] = a.w;
    }
#pragma unroll
    for (int q = 0; q < 4; ++q) {
      float4v a = __builtin_nontemporal_load(e4 + 4 + q);
      xb[q * 4 + 0] = a.x; xb[q * 4 + 1] = a.y; xb[q * 4 + 2] = a.z; xb[q * 4 + 3] = a.w;
    }
  }

  float predA, predB, asnA, asnB;
  float pbA[6], pbB[6];
  compute_token(xa, (unsigned)t0, rw, rb, predA, pbA, asnA);
  compute_token(xb, (unsigned)(t0 + 1), rw, rb, predB, pbB, asnB);

  // ---- stores: all vectorized, nontemporal ----
  float2v* pred2 = reinterpret_cast<float2v*>(out) + tid;
  {
    float2v v; v.x = predA; v.y = predB;
    __builtin_nontemporal_store(v, pred2);
  }

  float4v* po = reinterpret_cast<float4v*>(out + ntok) + (size_t)tid * 3;
  {
    float4v v0; v0.x = pbA[0]; v0.y = pbA[1]; v0.z = pbA[2]; v0.w = pbA[3];
    float4v v1; v1.x = pbA[4]; v1.y = pbA[5]; v1.z = pbB[0]; v1.w = pbB[1];
    float4v v2; v2.x = pbB[2]; v2.y = pbB[3]; v2.z = pbB[4]; v2.w = pbB[5];
    __builtin_nontemporal_store(v0, po + 0);
    __builtin_nontemporal_store(v1, po + 1);
    __builtin_nontemporal_store(v2, po + 2);
  }

  float2v* asn2 = reinterpret_cast<float2v*>(out + (size_t)ntok * 7) + tid;
  {
    float2v v; v.x = asnA; v.y = asnB;
    __builtin_nontemporal_store(v, asn2);
  }
}

extern "C" void kernel_launch(void* const* d_in, const int* in_sizes, int n_in,
                              void* d_out, int out_size, void* d_ws, size_t ws_size,
                              hipStream_t stream) {
  const float* emb = (const float*)d_in[0];
  const float* rw = (const float*)d_in[3];
  const float* rb = (const float*)d_in[4];
  float* out = (float*)d_out;
  int ntok = in_sizes[0] / 16;  // B*S
  int nthreads = (ntok + 1) / 2;
  int block = 256;
  int grid = (nthreads + block - 1) / block;
  hipLaunchKernelGGL(finance_moe_kernel, dim3(grid), dim3(block), 0, stream,
                     emb, rw, rb, out, ntok);
}

// Round 8
// 24.952 us; speedup vs baseline: 1.7072x; 1.7072x over previous
//
#include <hip/hip_runtime.h>
#include <math.h>

typedef float float4v __attribute__((ext_vector_type(4)));
typedef float float2v __attribute__((ext_vector_type(2)));

__device__ __forceinline__ unsigned rotl32(unsigned v, int n) {
  return (v << n) | (v >> (32 - n));
}

__device__ __forceinline__ float frcp(float x) { return __builtin_amdgcn_rcpf(x); }

__device__ __forceinline__ float ftanh(float x) {
  float t = __expf(2.0f * x);
  return 1.0f - 2.0f * frcp(t + 1.0f);
}

__device__ __forceinline__ float fsigmoid(float x) {
  return frcp(1.0f + __expf(-x));
}

// jax.random.normal(key(42), (n,), f32)[idx], partitionable threefry scheme.
__device__ __forceinline__ float jax_threefry_normal42_part(unsigned idx) {
  const unsigned ks0 = 0u;
  const unsigned ks1 = 42u;
  const unsigned ks2 = 0x1BD11BDAu ^ 42u;
  unsigned x0 = 0u + ks0;
  unsigned x1 = idx + ks1;
  const unsigned ks[3] = {ks0, ks1, ks2};
  const int rA[4] = {13, 15, 26, 6};
  const int rB[4] = {17, 29, 16, 24};
#pragma unroll
  for (int i = 0; i < 5; ++i) {
    const int* r = (i & 1) ? rB : rA;
#pragma unroll
    for (int k = 0; k < 4; ++k) {
      x0 += x1;
      x1 = rotl32(x1, r[k]);
      x1 ^= x0;
    }
    x0 += ks[(i + 1) % 3];
    x1 += ks[(i + 2) % 3] + (unsigned)(i + 1);
  }
  unsigned bits = x0 ^ x1;
  float u01 = __uint_as_float((bits >> 9) | 0x3f800000u) - 1.0f;
  const float lo = -0.99999994f;
  float u = fmaxf(lo, fmaf(u01, 2.0f, lo));
  float w = -__logf(1.0f - u * u);
  float p;
  if (w < 5.0f) {
    w = w - 2.5f;
    p = 2.81022636e-08f;
    p = fmaf(p, w, 3.43273939e-07f);
    p = fmaf(p, w, -3.5233877e-06f);
    p = fmaf(p, w, -4.39150654e-06f);
    p = fmaf(p, w, 0.00021858087f);
    p = fmaf(p, w, -0.00125372503f);
    p = fmaf(p, w, -0.00417768164f);
    p = fmaf(p, w, 0.246640727f);
    p = fmaf(p, w, 1.50140941f);
  } else {
    w = sqrtf(w) - 3.0f;
    p = -0.000200214257f;
    p = fmaf(p, w, 0.000100950558f);
    p = fmaf(p, w, 0.00134934322f);
    p = fmaf(p, w, -0.00367342844f);
    p = fmaf(p, w, 0.00573950773f);
    p = fmaf(p, w, -0.0076224613f);
    p = fmaf(p, w, 0.00943887047f);
    p = fmaf(p, w, 1.00167406f);
    p = fmaf(p, w, 2.83297682f);
  }
  return 1.41421354f * (p * u);
}

// Per-token computation: pred, pb[6], assignment
__device__ __forceinline__ void compute_token(
    const float* __restrict__ x, unsigned t,
    const float* __restrict__ rw, const float* __restrict__ rb,
    float& pred, float* pb, float& asn) {
  // router logits (f32)
  float lg[6];
#pragma unroll
  for (int d = 0; d < 6; ++d) {
    float acc = 0.0f;
#pragma unroll
    for (int h = 0; h < 16; ++h) acc = fmaf(x[h], rw[d * 16 + h], acc);
    lg[d] = acc + rb[d];
  }

  // argmax with f64 fallback for near-ties (match f64 np reference)
  int a1 = 0, a2 = 0;
  float b1 = lg[0], b2 = -1e30f;
#pragma unroll
  for (int d = 1; d < 6; ++d) {
    if (lg[d] > b1) { b2 = b1; a2 = a1; b1 = lg[d]; a1 = d; }
    else if (lg[d] > b2) { b2 = lg[d]; a2 = d; }
  }
  int amax = a1;
  if (b1 - b2 < 2e-5f) {
    double A = 0.0, B = 0.0;
#pragma unroll
    for (int h = 0; h < 16; ++h) {
      A = fma((double)x[h], (double)rw[a1 * 16 + h], A);
      B = fma((double)x[h], (double)rw[a2 * 16 + h], B);
    }
    A += (double)rb[a1];
    B += (double)rb[a2];
    amax = (B > A || (B == A && a2 < a1)) ? a2 : a1;
  }

  // softmax (routing_probs forward == probs_base)
  float m = lg[0];
#pragma unroll
  for (int d = 1; d < 6; ++d) m = fmaxf(m, lg[d]);
  float se = 0.0f;
  float eb[6];
#pragma unroll
  for (int d = 0; d < 6; ++d) { eb[d] = __expf(lg[d] - m); se += eb[d]; }
  float inv_se = frcp(se);
#pragma unroll
  for (int d = 0; d < 6; ++d) pb[d] = eb[d] * inv_se;

  // expert predictions
  float sum = 0.0f;
#pragma unroll
  for (int h = 0; h < 16; ++h) sum += x[h];
  float mean = sum * (1.0f / 16.0f);
  float ss = 0.0f;
#pragma unroll
  for (int h = 0; h < 16; ++h) {
    float dv = x[h] - mean;
    ss += dv * dv;
  }
  float stdv = sqrtf(ss * (1.0f / 15.0f));  // ddof=1

  float s4 = ((x[0] + x[1]) + x[2]) + x[3];
  float s6 = ((((x[0] + x[1]) + x[2]) + x[3]) + x[4]) + x[5];
  float s610 = ((x[6] + x[7]) + x[8]) + x[9];
  float s8 = s6 + x[6] + x[7];

  float sig = fsigmoid(mean);
  float p0 = ftanh(s4 * 0.25f) * (1.0f + stdv);
  float p1 = sig * 0.3f - 0.15f;
  float p2 = (s6 * (1.0f / 6.0f)) * 0.8f + __sinf((s610 * 0.25f) * 3.14159f) * 0.4f;
  float noise = jax_threefry_normal42_part(t) * 0.05f;
  float p3 = ftanh(s8 * 0.125f) * 0.9f + noise;
  float r4 = fmaxf(mean, 0.0f);
  float p4 = __expf(1.2f * __logf(r4)) + stdv * 2.5f - 0.5f;
  float p5 = sig * 0.4f + ftanh(stdv) * 0.2f;

  pred = (amax == 0) ? p0
       : (amax == 1) ? p1
       : (amax == 2) ? p2
       : (amax == 3) ? p3
       : (amax == 4) ? p4
                     : p5;
  asn = (float)amax;
}

__global__ __launch_bounds__(256) void finance_moe_kernel(
    const float* __restrict__ emb,  // (ntok, 16)
    const float* __restrict__ rw,   // (6, 16)
    const float* __restrict__ rb,   // (6,)
    float* __restrict__ out,        // [ntok pred][ntok*6 probs][ntok assign]
    int ntok) {
  int tid = blockIdx.x * blockDim.x + threadIdx.x;
  int t0 = tid * 2;
  if (t0 + 1 >= ntok) {
    if (t0 < ntok) {
      // odd tail (not hit for ntok = 2^20, kept for safety)
      float x[16];
      const float4v* e4 = reinterpret_cast<const float4v*>(emb) + (size_t)t0 * 4;
#pragma unroll
      for (int q = 0; q < 4; ++q) {
        float4v a = e4[q];
        x[q * 4 + 0] = a.x; x[q * 4 + 1] = a.y; x[q * 4 + 2] = a.z; x[q * 4 + 3] = a.w;
      }
      float pred, asn, pb[6];
      compute_token(x, (unsigned)t0, rw, rb, pred, pb, asn);
      out[t0] = pred;
      for (int d = 0; d < 6; ++d) out[ntok + t0 * 6 + d] = pb[d];
      out[(size_t)ntok * 7 + t0] = asn;
    }
    return;
  }

  // ---- load two tokens' embeddings (128B contiguous per thread; L1 serves
  //      the 8 pieces from 2 lines) ----
  float xa[16], xb[16];
  {
    const float4v* e4 = reinterpret_cast<const float4v*>(emb) + (size_t)t0 * 4;
#pragma unroll
    for (int q = 0; q < 4; ++q) {
      float4v a = e4[q];
      xa[q * 4 + 0] = a.x; xa[q * 4 + 1] = a.y; xa[q * 4 + 2] = a.z; xa[q * 4 + 3] = a.w;
    }
#pragma unroll
    for (int q = 0; q < 4; ++q) {
      float4v a = e4[4 + q];
      xb[q * 4 + 0] = a.x; xb[q * 4 + 1] = a.y; xb[q * 4 + 2] = a.z; xb[q * 4 + 3] = a.w;
    }
  }

  float predA, predB, asnA, asnB;
  float pbA[6], pbB[6];
  compute_token(xa, (unsigned)t0, rw, rb, predA, pbA, asnA);
  compute_token(xb, (unsigned)(t0 + 1), rw, rb, predB, pbB, asnB);

  // ---- stores: vectorized, cached ----
  float2v* pred2 = reinterpret_cast<float2v*>(out) + tid;
  {
    float2v v; v.x = predA; v.y = predB;
    *pred2 = v;
  }

  float4v* po = reinterpret_cast<float4v*>(out + ntok) + (size_t)tid * 3;
  {
    float4v v0; v0.x = pbA[0]; v0.y = pbA[1]; v0.z = pbA[2]; v0.w = pbA[3];
    float4v v1; v1.x = pbA[4]; v1.y = pbA[5]; v1.z = pbB[0]; v1.w = pbB[1];
    float4v v2; v2.x = pbB[2]; v2.y = pbB[3]; v2.z = pbB[4]; v2.w = pbB[5];
    po[0] = v0;
    po[1] = v1;
    po[2] = v2;
  }

  float2v* asn2 = reinterpret_cast<float2v*>(out + (size_t)ntok * 7) + tid;
  {
    float2v v; v.x = asnA; v.y = asnB;
    *asn2 = v;
  }
}

extern "C" void kernel_launch(void* const* d_in, const int* in_sizes, int n_in,
                              void* d_out, int out_size, void* d_ws, size_t ws_size,
                              hipStream_t stream) {
  const float* emb = (const float*)d_in[0];
  const float* rw = (const float*)d_in[3];
  const float* rb = (const float*)d_in[4];
  float* out = (float*)d_out;
  int ntok = in_sizes[0] / 16;  // B*S
  int nthreads = (ntok + 1) / 2;
  int block = 256;
  int grid = (nthreads + block - 1) / block;
  hipLaunchKernelGGL(finance_moe_kernel, dim3(grid), dim3(block), 0, stream,
                     emb, rw, rb, out, ntok);
}

// Round 9
// 23.999 us; speedup vs baseline: 1.7750x; 1.0397x over previous
//
#include <hip/hip_runtime.h>
#include <math.h>

typedef float float4v __attribute__((ext_vector_type(4)));
typedef float float2v __attribute__((ext_vector_type(2)));

__device__ __forceinline__ unsigned rotl32(unsigned v, int n) {
  return (v << n) | (v >> (32 - n));
}

__device__ __forceinline__ float frcp(float x) { return __builtin_amdgcn_rcpf(x); }

__device__ __forceinline__ float ftanh(float x) {
  float t = __expf(2.0f * x);
  return 1.0f - 2.0f * frcp(t + 1.0f);
}

__device__ __forceinline__ float fsigmoid(float x) {
  return frcp(1.0f + __expf(-x));
}

// jax.random.normal(key(42), (n,), f32)[idx], partitionable threefry scheme.
__device__ __forceinline__ float jax_threefry_normal42_part(unsigned idx) {
  const unsigned ks0 = 0u;
  const unsigned ks1 = 42u;
  const unsigned ks2 = 0x1BD11BDAu ^ 42u;
  unsigned x0 = 0u + ks0;
  unsigned x1 = idx + ks1;
  const unsigned ks[3] = {ks0, ks1, ks2};
  const int rA[4] = {13, 15, 26, 6};
  const int rB[4] = {17, 29, 16, 24};
#pragma unroll
  for (int i = 0; i < 5; ++i) {
    const int* r = (i & 1) ? rB : rA;
#pragma unroll
    for (int k = 0; k < 4; ++k) {
      x0 += x1;
      x1 = rotl32(x1, r[k]);
      x1 ^= x0;
    }
    x0 += ks[(i + 1) % 3];
    x1 += ks[(i + 2) % 3] + (unsigned)(i + 1);
  }
  unsigned bits = x0 ^ x1;
  float u01 = __uint_as_float((bits >> 9) | 0x3f800000u) - 1.0f;
  const float lo = -0.99999994f;
  float u = fmaxf(lo, fmaf(u01, 2.0f, lo));
  float w = -__logf(1.0f - u * u);
  float p;
  if (w < 5.0f) {
    w = w - 2.5f;
    p = 2.81022636e-08f;
    p = fmaf(p, w, 3.43273939e-07f);
    p = fmaf(p, w, -3.5233877e-06f);
    p = fmaf(p, w, -4.39150654e-06f);
    p = fmaf(p, w, 0.00021858087f);
    p = fmaf(p, w, -0.00125372503f);
    p = fmaf(p, w, -0.00417768164f);
    p = fmaf(p, w, 0.246640727f);
    p = fmaf(p, w, 1.50140941f);
  } else {
    w = sqrtf(w) - 3.0f;
    p = -0.000200214257f;
    p = fmaf(p, w, 0.000100950558f);
    p = fmaf(p, w, 0.00134934322f);
    p = fmaf(p, w, -0.00367342844f);
    p = fmaf(p, w, 0.00573950773f);
    p = fmaf(p, w, -0.0076224613f);
    p = fmaf(p, w, 0.00943887047f);
    p = fmaf(p, w, 1.00167406f);
    p = fmaf(p, w, 2.83297682f);
  }
  return 1.41421354f * (p * u);
}

// Per-token computation: pred, pb[6], assignment
__device__ __forceinline__ void compute_token(
    const float* __restrict__ x, unsigned t,
    const float* __restrict__ rw, const float* __restrict__ rb,
    float& pred, float* pb, float& asn) {
  // router logits (f32)
  float lg[6];
#pragma unroll
  for (int d = 0; d < 6; ++d) {
    float acc = 0.0f;
#pragma unroll
    for (int h = 0; h < 16; ++h) acc = fmaf(x[h], rw[d * 16 + h], acc);
    lg[d] = acc + rb[d];
  }

  // argmax with f64 fallback for near-ties (match f64 np reference)
  int a1 = 0, a2 = 0;
  float b1 = lg[0], b2 = -1e30f;
#pragma unroll
  for (int d = 1; d < 6; ++d) {
    if (lg[d] > b1) { b2 = b1; a2 = a1; b1 = lg[d]; a1 = d; }
    else if (lg[d] > b2) { b2 = lg[d]; a2 = d; }
  }
  int amax = a1;
  if (b1 - b2 < 2e-5f) {
    double A = 0.0, B = 0.0;
#pragma unroll
    for (int h = 0; h < 16; ++h) {
      A = fma((double)x[h], (double)rw[a1 * 16 + h], A);
      B = fma((double)x[h], (double)rw[a2 * 16 + h], B);
    }
    A += (double)rb[a1];
    B += (double)rb[a2];
    amax = (B > A || (B == A && a2 < a1)) ? a2 : a1;
  }

  // softmax (routing_probs forward == probs_base)
  float m = lg[0];
#pragma unroll
  for (int d = 1; d < 6; ++d) m = fmaxf(m, lg[d]);
  float se = 0.0f;
  float eb[6];
#pragma unroll
  for (int d = 0; d < 6; ++d) { eb[d] = __expf(lg[d] - m); se += eb[d]; }
  float inv_se = frcp(se);
#pragma unroll
  for (int d = 0; d < 6; ++d) pb[d] = eb[d] * inv_se;

  // expert predictions
  float sum = 0.0f;
#pragma unroll
  for (int h = 0; h < 16; ++h) sum += x[h];
  float mean = sum * (1.0f / 16.0f);
  float ss = 0.0f;
#pragma unroll
  for (int h = 0; h < 16; ++h) {
    float dv = x[h] - mean;
    ss += dv * dv;
  }
  float stdv = sqrtf(ss * (1.0f / 15.0f));  // ddof=1

  float s4 = ((x[0] + x[1]) + x[2]) + x[3];
  float s6 = ((((x[0] + x[1]) + x[2]) + x[3]) + x[4]) + x[5];
  float s610 = ((x[6] + x[7]) + x[8]) + x[9];
  float s8 = s6 + x[6] + x[7];

  float sig = fsigmoid(mean);
  float p0 = ftanh(s4 * 0.25f) * (1.0f + stdv);
  float p1 = sig * 0.3f - 0.15f;
  float p2 = (s6 * (1.0f / 6.0f)) * 0.8f + __sinf((s610 * 0.25f) * 3.14159f) * 0.4f;
  float noise = jax_threefry_normal42_part(t) * 0.05f;
  float p3 = ftanh(s8 * 0.125f) * 0.9f + noise;
  float r4 = fmaxf(mean, 0.0f);
  float p4 = __expf(1.2f * __logf(r4)) + stdv * 2.5f - 0.5f;
  float p5 = sig * 0.4f + ftanh(stdv) * 0.2f;

  pred = (amax == 0) ? p0
       : (amax == 1) ? p1
       : (amax == 2) ? p2
       : (amax == 3) ? p3
       : (amax == 4) ? p4
                     : p5;
  asn = (float)amax;
}

__device__ __forceinline__ void load16(const float* __restrict__ emb, int t,
                                       float* __restrict__ x) {
  const float4v* e4 = reinterpret_cast<const float4v*>(emb) + (size_t)t * 4;
#pragma unroll
  for (int q = 0; q < 4; ++q) {
    float4v a = e4[q];
    x[q * 4 + 0] = a.x; x[q * 4 + 1] = a.y; x[q * 4 + 2] = a.z; x[q * 4 + 3] = a.w;
  }
}

__device__ __forceinline__ void store_token(float* __restrict__ out, int ntok,
                                            int t, float pred, const float* pb,
                                            float asn) {
  out[t] = pred;
  float2v* po = reinterpret_cast<float2v*>(out + ntok) + (size_t)t * 3;
  float2v v0; v0.x = pb[0]; v0.y = pb[1];
  float2v v1; v1.x = pb[2]; v1.y = pb[3];
  float2v v2; v2.x = pb[4]; v2.y = pb[5];
  po[0] = v0;
  po[1] = v1;
  po[2] = v2;
  out[(size_t)ntok * 7 + t] = asn;
}

__global__ __launch_bounds__(256) void finance_moe_kernel(
    const float* __restrict__ emb,  // (ntok, 16)
    const float* __restrict__ rw,   // (6, 16)
    const float* __restrict__ rb,   // (6,)
    float* __restrict__ out,        // [ntok pred][ntok*6 probs][ntok assign]
    int ntok) {
  int half = ntok >> 1;  // ntok = 2^20, even
  int tid = blockIdx.x * blockDim.x + threadIdx.x;
  if (tid >= half) return;
  int tA = tid;          // first half
  int tB = tid + half;   // second half — same lane-contiguous pattern, far apart

  // ---- loads: 8 float4 instrs, each lane-contiguous (stride 64B) ----
  float xa[16], xb[16];
  load16(emb, tA, xa);
  load16(emb, tB, xb);

  float predA, predB, asnA, asnB;
  float pbA[6], pbB[6];
  compute_token(xa, (unsigned)tA, rw, rb, predA, pbA, asnA);
  compute_token(xb, (unsigned)tB, rw, rb, predB, pbB, asnB);

  store_token(out, ntok, tA, predA, pbA, asnA);
  store_token(out, ntok, tB, predB, pbB, asnB);
}

extern "C" void kernel_launch(void* const* d_in, const int* in_sizes, int n_in,
                              void* d_out, int out_size, void* d_ws, size_t ws_size,
                              hipStream_t stream) {
  const float* emb = (const float*)d_in[0];
  const float* rw = (const float*)d_in[3];
  const float* rb = (const float*)d_in[4];
  float* out = (float*)d_out;
  int ntok = in_sizes[0] / 16;  // B*S
  int nthreads = (ntok + 1) / 2;
  int block = 256;
  int grid = (nthreads + block - 1) / block;
  hipLaunchKernelGGL(finance_moe_kernel, dim3(grid), dim3(block), 0, stream,
                     emb, rw, rb, out, ntok);
}

// Round 10
// 21.657 us; speedup vs baseline: 1.9670x; 1.1082x over previous
//
#include <hip/hip_runtime.h>
#include <math.h>

typedef float float4v __attribute__((ext_vector_type(4)));
typedef float float2v __attribute__((ext_vector_type(2)));

__device__ __forceinline__ unsigned rotl32(unsigned v, int n) {
  return (v << n) | (v >> (32 - n));
}

__device__ __forceinline__ float frcp(float x) { return __builtin_amdgcn_rcpf(x); }

__device__ __forceinline__ float ftanh(float x) {
  float t = __expf(2.0f * x);
  return 1.0f - 2.0f * frcp(t + 1.0f);
}

__device__ __forceinline__ float fsigmoid(float x) {
  return frcp(1.0f + __expf(-x));
}

// jax.random.normal(key(42), (n,), f32)[idx], partitionable threefry scheme.
// Depends ONLY on idx — callable before data loads land.
__device__ __forceinline__ float jax_threefry_normal42_part(unsigned idx) {
  const unsigned ks0 = 0u;
  const unsigned ks1 = 42u;
  const unsigned ks2 = 0x1BD11BDAu ^ 42u;
  unsigned x0 = 0u + ks0;
  unsigned x1 = idx + ks1;
  const unsigned ks[3] = {ks0, ks1, ks2};
  const int rA[4] = {13, 15, 26, 6};
  const int rB[4] = {17, 29, 16, 24};
#pragma unroll
  for (int i = 0; i < 5; ++i) {
    const int* r = (i & 1) ? rB : rA;
#pragma unroll
    for (int k = 0; k < 4; ++k) {
      x0 += x1;
      x1 = rotl32(x1, r[k]);
      x1 ^= x0;
    }
    x0 += ks[(i + 1) % 3];
    x1 += ks[(i + 2) % 3] + (unsigned)(i + 1);
  }
  unsigned bits = x0 ^ x1;
  float u01 = __uint_as_float((bits >> 9) | 0x3f800000u) - 1.0f;
  const float lo = -0.99999994f;
  float u = fmaxf(lo, fmaf(u01, 2.0f, lo));
  float w = -__logf(1.0f - u * u);
  float p;
  if (w < 5.0f) {
    w = w - 2.5f;
    p = 2.81022636e-08f;
    p = fmaf(p, w, 3.43273939e-07f);
    p = fmaf(p, w, -3.5233877e-06f);
    p = fmaf(p, w, -4.39150654e-06f);
    p = fmaf(p, w, 0.00021858087f);
    p = fmaf(p, w, -0.00125372503f);
    p = fmaf(p, w, -0.00417768164f);
    p = fmaf(p, w, 0.246640727f);
    p = fmaf(p, w, 1.50140941f);
  } else {
    w = sqrtf(w) - 3.0f;
    p = -0.000200214257f;
    p = fmaf(p, w, 0.000100950558f);
    p = fmaf(p, w, 0.00134934322f);
    p = fmaf(p, w, -0.00367342844f);
    p = fmaf(p, w, 0.00573950773f);
    p = fmaf(p, w, -0.0076224613f);
    p = fmaf(p, w, 0.00943887047f);
    p = fmaf(p, w, 1.00167406f);
    p = fmaf(p, w, 2.83297682f);
  }
  return 1.41421354f * (p * u);
}

__global__ __launch_bounds__(256) void finance_moe_kernel(
    const float* __restrict__ emb,  // (ntok, 16)
    const float* __restrict__ rw,   // (6, 16)
    const float* __restrict__ rb,   // (6,)
    float* __restrict__ out,        // [ntok pred][ntok*6 probs][ntok assign]
    int ntok) {
  int t = blockIdx.x * blockDim.x + threadIdx.x;
  if (t >= ntok) return;

  // ---- issue embedding loads first (4 x dwordx4, lane stride 64B) ----
  const float4v* e4 = reinterpret_cast<const float4v*>(emb) + (size_t)t * 4;
  float4v a0 = e4[0];
  float4v a1 = e4[1];
  float4v a2 = e4[2];
  float4v a3 = e4[3];

  // ---- index-only work overlapped with load latency: threefry noise ----
  float noise = jax_threefry_normal42_part((unsigned)t) * 0.05f;

  float x[16];
  x[0] = a0.x; x[1] = a0.y; x[2] = a0.z; x[3] = a0.w;
  x[4] = a1.x; x[5] = a1.y; x[6] = a1.z; x[7] = a1.w;
  x[8] = a2.x; x[9] = a2.y; x[10] = a2.z; x[11] = a2.w;
  x[12] = a3.x; x[13] = a3.y; x[14] = a3.z; x[15] = a3.w;

  // ---- router logits (f32) ----
  float lg[6];
#pragma unroll
  for (int d = 0; d < 6; ++d) {
    float acc = 0.0f;
#pragma unroll
    for (int h = 0; h < 16; ++h) acc = fmaf(x[h], rw[d * 16 + h], acc);
    lg[d] = acc + rb[d];
  }

  // ---- argmax: f32 top-2 gap test; f64 fallback for near-ties ----
  int a1i = 0, a2i = 0;
  float b1 = lg[0], b2 = -1e30f;
#pragma unroll
  for (int d = 1; d < 6; ++d) {
    if (lg[d] > b1) { b2 = b1; a2i = a1i; b1 = lg[d]; a1i = d; }
    else if (lg[d] > b2) { b2 = lg[d]; a2i = d; }
  }
  int amax = a1i;
  if (b1 - b2 < 2e-5f) {
    double A = 0.0, B = 0.0;
#pragma unroll
    for (int h = 0; h < 16; ++h) {
      A = fma((double)x[h], (double)rw[a1i * 16 + h], A);
      B = fma((double)x[h], (double)rw[a2i * 16 + h], B);
    }
    A += (double)rb[a1i];
    B += (double)rb[a2i];
    amax = (B > A || (B == A && a2i < a1i)) ? a2i : a1i;
  }

  // ---- probs_base = softmax(logits); routing_probs forward == probs_base ----
  float m = lg[0];
#pragma unroll
  for (int d = 1; d < 6; ++d) m = fmaxf(m, lg[d]);
  float eb[6], se = 0.0f;
#pragma unroll
  for (int d = 0; d < 6; ++d) { eb[d] = __expf(lg[d] - m); se += eb[d]; }
  float inv_se = frcp(se);
  float pb[6];
#pragma unroll
  for (int d = 0; d < 6; ++d) pb[d] = eb[d] * inv_se;

  // ---- expert predictions (straight-line, select at end) ----
  float sum = 0.0f;
#pragma unroll
  for (int h = 0; h < 16; ++h) sum += x[h];
  float mean = sum * (1.0f / 16.0f);
  float ss = 0.0f;
#pragma unroll
  for (int h = 0; h < 16; ++h) {
    float dv = x[h] - mean;
    ss += dv * dv;
  }
  float stdv = sqrtf(ss * (1.0f / 15.0f));  // ddof=1

  float s4 = ((x[0] + x[1]) + x[2]) + x[3];
  float s6 = ((((x[0] + x[1]) + x[2]) + x[3]) + x[4]) + x[5];
  float s610 = ((x[6] + x[7]) + x[8]) + x[9];
  float s8 = s6 + x[6] + x[7];

  float sig = fsigmoid(mean);
  float p0 = ftanh(s4 * 0.25f) * (1.0f + stdv);
  float p1 = sig * 0.3f - 0.15f;
  float p2 = (s6 * (1.0f / 6.0f)) * 0.8f + __sinf((s610 * 0.25f) * 3.14159f) * 0.4f;
  float p3 = ftanh(s8 * 0.125f) * 0.9f + noise;
  float r4 = fmaxf(mean, 0.0f);
  float p4 = __expf(1.2f * __logf(r4)) + stdv * 2.5f - 0.5f;
  float p5 = sig * 0.4f + ftanh(stdv) * 0.2f;

  float pred = (amax == 0) ? p0
             : (amax == 1) ? p1
             : (amax == 2) ? p2
             : (amax == 3) ? p3
             : (amax == 4) ? p4
                           : p5;

  // ---- stores ----
  out[t] = pred;
  float2v* po = reinterpret_cast<float2v*>(out + ntok) + (size_t)t * 3;
  float2v v0; v0.x = pb[0]; v0.y = pb[1];
  float2v v1; v1.x = pb[2]; v1.y = pb[3];
  float2v v2; v2.x = pb[4]; v2.y = pb[5];
  po[0] = v0;
  po[1] = v1;
  po[2] = v2;
  out[(size_t)ntok * 7 + t] = (float)amax;
}

extern "C" void kernel_launch(void* const* d_in, const int* in_sizes, int n_in,
                              void* d_out, int out_size, void* d_ws, size_t ws_size,
                              hipStream_t stream) {
  const float* emb = (const float*)d_in[0];
  const float* rw = (const float*)d_in[3];
  const float* rb = (const float*)d_in[4];
  float* out = (float*)d_out;
  int ntok = in_sizes[0] / 16;  // B*S
  int block = 256;
  int grid = (ntok + block - 1) / block;
  hipLaunchKernelGGL(finance_moe_kernel, dim3(grid), dim3(block), 0, stream,
                     emb, rw, rb, out, ntok);
}